// Round 1
// baseline (340.755 us; speedup 1.0000x reference)
//
#include <hip/hip_runtime.h>

typedef __attribute__((ext_vector_type(8))) short bf16x8;
typedef __attribute__((ext_vector_type(4))) float f32x4;

#define OUT0 524288           // B*G*E
#define SRC_CH_STRIDE 8388608 // B*G*G = 2*2048*2048

__device__ __forceinline__ unsigned short f2bf(float x){
    unsigned u = __builtin_bit_cast(unsigned, x);
    u += 0x7FFFu + ((u >> 16) & 1u);
    return (unsigned short)(u >> 16);
}

// ---------------- kernel 1: QKV projection ----------------
// grid (128 row-tiles of 32, 12 = 3 mats x 4 heads), block 256
// Q,K -> bf16 [b][g][head*32+k] ; V -> bf16 transposed [b][head*32+v][g]
__global__ __launch_bounds__(256) void qkv_kernel(
    const float* __restrict__ hsrc,
    const float* __restrict__ Wq, const float* __restrict__ Wk, const float* __restrict__ Wv,
    unsigned short* __restrict__ Qb, unsigned short* __restrict__ Kb, unsigned short* __restrict__ Vt)
{
    __shared__ float hs[32*128];
    __shared__ float ws[128*32];
    const int t = threadIdx.x;
    const int g0 = blockIdx.x * 32;
    const int mat = blockIdx.y;
    const int mt = mat >> 2, head = mat & 3;
    {
        const float4* s = (const float4*)(hsrc + g0*128);
        float4* d = (float4*)hs;
        #pragma unroll
        for (int i=0;i<4;i++) d[t + i*256] = s[t + i*256];
        const float* W = (mt==0?Wq:(mt==1?Wk:Wv)) + head*4096;
        const float4* s2 = (const float4*)W;
        float4* d2 = (float4*)ws;
        #pragma unroll
        for (int i=0;i<4;i++) d2[t + i*256] = s2[t + i*256];
    }
    __syncthreads();
    const int r = t >> 3;          // 0..31 row in tile
    const int k0 = (t & 7) * 4;    // 0..28 out col group
    float a0=0.f,a1=0.f,a2=0.f,a3=0.f;
    const float* hr = hs + r*128;
    #pragma unroll 8
    for (int d=0; d<128; d++){
        float hv = hr[d];
        float4 w4 = *(const float4*)(ws + d*32 + k0);
        a0 = fmaf(hv, w4.x, a0); a1 = fmaf(hv, w4.y, a1);
        a2 = fmaf(hv, w4.z, a2); a3 = fmaf(hv, w4.w, a3);
    }
    const int row_g = g0 + r;
    if (mt == 2){
        const int b = row_g >> 11, g = row_g & 2047;
        unsigned short* dst = Vt + ((b*128 + head*32 + k0) * 2048) + g;
        dst[0] = f2bf(a0); dst[2048] = f2bf(a1); dst[4096] = f2bf(a2); dst[6144] = f2bf(a3);
    } else {
        unsigned short* dst = (mt==0?Qb:Kb) + row_g*128 + head*32 + k0;
        dst[0]=f2bf(a0); dst[1]=f2bf(a1); dst[2]=f2bf(a2); dst[3]=f2bf(a3);
    }
}

// ---------------- kernel 2: fused attention ----------------
// grid (128 q-tiles of 16, B=2), block 256 = 4 waves (wave == head)
__global__ __launch_bounds__(256) void attn_kernel(
    const float* __restrict__ src,
    const unsigned short* __restrict__ Qb,
    const unsigned short* __restrict__ Kb,
    const unsigned short* __restrict__ Vt,
    const float* __restrict__ w1g, const float* __restrict__ b1g,
    const float* __restrict__ w2g, const float* __restrict__ b2g,
    const float* __restrict__ Wout,
    float* __restrict__ out)
{
    __shared__ __align__(16) float S_lds[4*16*68];            // scores/logits, +4 pad
    __shared__ __align__(16) unsigned short Pb_lds[4*16*72];  // P bf16, +8 pad
    __shared__ __align__(16) float wt[112];                   // MLP weights
    __shared__ __align__(16) float m_lds[64];
    __shared__ __align__(16) float l_lds[64];
    __shared__ __align__(16) float alpha_lds[64];

    const int t = threadIdx.x;
    const int lane = t & 63;
    const int c = t >> 6;            // head = wave
    const int quad = lane >> 4;
    const int lrow = lane & 15;
    const int q0 = blockIdx.x * 16;
    const int b = blockIdx.y;

    if (t < 64) wt[t] = w1g[t];
    else if (t < 72) wt[t] = b1g[t-64];
    else if (t < 104) wt[t] = w2g[t-72];
    else if (t < 108) wt[t] = b2g[t-104];
    if (t < 64){ m_lds[t] = -1e30f; l_lds[t] = 0.f; alpha_lds[t] = 0.f; }

    // Q fragment: A[m=lane&15][k=quad*8+j], kd=32 exactly one K-step
    const bf16x8 qf = *(const bf16x8*)(Qb + (b*2048 + q0 + lrow)*128 + c*32 + quad*8);

    const int mq = t >> 4;           // MLP cell row 0..15
    const int mp = (t & 15) * 4;     // MLP cell col group
    const int srcbase0 = (b*2048 + q0 + mq)*2048 + mp;

    f32x4 o0 = {0.f,0.f,0.f,0.f};    // v 0..15
    f32x4 o1 = {0.f,0.f,0.f,0.f};    // v 16..31
    const f32x4 zero4 = {0.f,0.f,0.f,0.f};

    __syncthreads();

    for (int p0 = 0; p0 < 2048; p0 += 64){
        // ---- phase 1: src loads (+write-through) and score MFMAs ----
        float4 r4[4];
        #pragma unroll
        for (int ch=0; ch<4; ch++)
            r4[ch] = *(const float4*)(src + srcbase0 + ch*SRC_CH_STRIDE + p0);
        #pragma unroll
        for (int sub=0; sub<4; sub++){
            const bf16x8 kf = *(const bf16x8*)(Kb + (b*2048 + p0 + sub*16 + lrow)*128 + c*32 + quad*8);
            f32x4 sacc = __builtin_amdgcn_mfma_f32_16x16x32_bf16(qf, kf, zero4, 0, 0, 0);
            float* Sp = S_lds + (c*16 + quad*4)*68 + sub*16 + lrow;
            Sp[0] = sacc[0]; Sp[68] = sacc[1]; Sp[136] = sacc[2]; Sp[204] = sacc[3];
        }
        #pragma unroll
        for (int ch=0; ch<4; ch++)
            *(float4*)(out + OUT0 + srcbase0 + ch*SRC_CH_STRIDE + p0) = r4[ch];
        __syncthreads();

        // ---- phase 3: per-cell MLP (8 -> relu8 -> 4), logits back into S in place ----
        {
            float xs[4][4], xr[4][4];
            #pragma unroll
            for (int ch=0; ch<4; ch++){
                float4 v = *(const float4*)(S_lds + (ch*16 + mq)*68 + mp);
                xs[ch][0]=v.x; xs[ch][1]=v.y; xs[ch][2]=v.z; xs[ch][3]=v.w;
                xr[ch][0]=r4[ch].x; xr[ch][1]=r4[ch].y; xr[ch][2]=r4[ch].z; xr[ch][3]=r4[ch].w;
            }
            float z[4][4];
            #pragma unroll
            for (int cc=0; cc<4; cc++){
                float bb = wt[104+cc];
                #pragma unroll
                for (int cell=0; cell<4; cell++) z[cc][cell] = bb;
            }
            #pragma unroll
            for (int j=0; j<8; j++){
                float w0 = wt[j*8+0], w1v = wt[j*8+1], w2v = wt[j*8+2], w3 = wt[j*8+3];
                float w4v = wt[j*8+4], w5 = wt[j*8+5], w6 = wt[j*8+6], w7 = wt[j*8+7];
                float bj = wt[64+j];
                float hcell[4];
                #pragma unroll
                for (int cell=0; cell<4; cell++){
                    float v = bj;
                    v = fmaf(w0, xs[0][cell], v);
                    v = fmaf(w1v, xs[1][cell], v);
                    v = fmaf(w2v, xs[2][cell], v);
                    v = fmaf(w3, xs[3][cell], v);
                    v = fmaf(w4v, xr[0][cell], v);
                    v = fmaf(w5, xr[1][cell], v);
                    v = fmaf(w6, xr[2][cell], v);
                    v = fmaf(w7, xr[3][cell], v);
                    hcell[cell] = fmaxf(v, 0.f);
                }
                #pragma unroll
                for (int cc=0; cc<4; cc++){
                    float wv = wt[72 + cc*8 + j];
                    #pragma unroll
                    for (int cell=0; cell<4; cell++) z[cc][cell] = fmaf(wv, hcell[cell], z[cc][cell]);
                }
            }
            #pragma unroll
            for (int ch=0; ch<4; ch++){
                float4 v; v.x=z[ch][0]; v.y=z[ch][1]; v.z=z[ch][2]; v.w=z[ch][3];
                *(float4*)(S_lds + (ch*16 + mq)*68 + mp) = v;
            }
        }
        __syncthreads();

        // ---- phase 5: online softmax over this 64-wide p-tile ----
        {
            const int rowid = t >> 2;        // flat (head*16+q), 4 lanes per row
            const int seg = t & 3;
            const float* Sp = S_lds + rowid*68 + seg*16;
            float4 xa = *(const float4*)(Sp);
            float4 xb = *(const float4*)(Sp+4);
            float4 xc = *(const float4*)(Sp+8);
            float4 xd = *(const float4*)(Sp+12);
            float x[16];
            x[0]=xa.x; x[1]=xa.y; x[2]=xa.z; x[3]=xa.w;
            x[4]=xb.x; x[5]=xb.y; x[6]=xb.z; x[7]=xb.w;
            x[8]=xc.x; x[9]=xc.y; x[10]=xc.z; x[11]=xc.w;
            x[12]=xd.x; x[13]=xd.y; x[14]=xd.z; x[15]=xd.w;
            float mloc = x[0];
            #pragma unroll
            for (int i=1;i<16;i++) mloc = fmaxf(mloc, x[i]);
            mloc = fmaxf(mloc, __shfl_xor(mloc, 1));
            mloc = fmaxf(mloc, __shfl_xor(mloc, 2));
            float m_old = m_lds[rowid];
            float m_new = fmaxf(m_old, mloc);
            float ssum = 0.f;
            unsigned pk[8];
            #pragma unroll
            for (int i=0;i<8;i++){
                float e0 = __expf(x[2*i] - m_new);
                float e1 = __expf(x[2*i+1] - m_new);
                ssum += e0 + e1;
                pk[i] = (unsigned)f2bf(e0) | ((unsigned)f2bf(e1) << 16);
            }
            ssum += __shfl_xor(ssum, 1);
            ssum += __shfl_xor(ssum, 2);
            uint4* Pp = (uint4*)(Pb_lds + rowid*72 + seg*16);
            Pp[0] = make_uint4(pk[0],pk[1],pk[2],pk[3]);
            Pp[1] = make_uint4(pk[4],pk[5],pk[6],pk[7]);
            if (seg == 0){
                float alpha = __expf(m_old - m_new);
                m_lds[rowid] = m_new;
                alpha_lds[rowid] = alpha;
                l_lds[rowid] = fmaf(l_lds[rowid], alpha, ssum);
            }
        }
        __syncthreads();

        // ---- phase 7: rescale O, P@V via MFMA (V read direct from global, transposed) ----
        {
            float4 a4 = *(const float4*)(alpha_lds + c*16 + quad*4);
            o0[0]*=a4.x; o0[1]*=a4.y; o0[2]*=a4.z; o0[3]*=a4.w;
            o1[0]*=a4.x; o1[1]*=a4.y; o1[2]*=a4.z; o1[3]*=a4.w;
            #pragma unroll
            for (int chunk=0; chunk<2; chunk++){
                const bf16x8 pf = *(const bf16x8*)(Pb_lds + (c*16 + lrow)*72 + chunk*32 + quad*8);
                const bf16x8 v0 = *(const bf16x8*)(Vt + (b*128 + c*32 + lrow)*2048 + p0 + chunk*32 + quad*8);
                const bf16x8 v1 = *(const bf16x8*)(Vt + (b*128 + c*32 + 16 + lrow)*2048 + p0 + chunk*32 + quad*8);
                o0 = __builtin_amdgcn_mfma_f32_16x16x32_bf16(pf, v0, o0, 0, 0, 0);
                o1 = __builtin_amdgcn_mfma_f32_16x16x32_bf16(pf, v1, o1, 0, 0, 0);
            }
        }
    }

    // ---- epilogue: normalize, stash heads in LDS, project with Wout ----
    {
        float4 l4 = *(const float4*)(l_lds + c*16 + quad*4);
        float i0 = 1.f/l4.x, i1 = 1.f/l4.y, i2 = 1.f/l4.z, i3 = 1.f/l4.w;
        o0[0]*=i0; o0[1]*=i1; o0[2]*=i2; o0[3]*=i3;
        o1[0]*=i0; o1[1]*=i1; o1[2]*=i2; o1[3]*=i3;
        #pragma unroll
        for (int r=0;r<4;r++){
            S_lds[(c*16 + quad*4 + r)*36 + lrow] = o0[r];
            S_lds[(c*16 + quad*4 + r)*36 + 16 + lrow] = o1[r];
        }
    }
    __syncthreads();
    {
        const int e0 = (t & 15) * 8;
        float acc[8];
        #pragma unroll
        for (int i=0;i<8;i++) acc[i]=0.f;
        #pragma unroll
        for (int cc=0; cc<4; cc++){
            const float* OhRow = S_lds + (cc*16 + mq)*36;
            const float* Wrow = Wout + cc*32*128 + e0;
            #pragma unroll 4
            for (int v=0; v<32; v++){
                float ov = OhRow[v];
                float4 wA = *(const float4*)(Wrow + v*128);
                float4 wB = *(const float4*)(Wrow + v*128 + 4);
                acc[0]=fmaf(ov,wA.x,acc[0]); acc[1]=fmaf(ov,wA.y,acc[1]);
                acc[2]=fmaf(ov,wA.z,acc[2]); acc[3]=fmaf(ov,wA.w,acc[3]);
                acc[4]=fmaf(ov,wB.x,acc[4]); acc[5]=fmaf(ov,wB.y,acc[5]);
                acc[6]=fmaf(ov,wB.z,acc[6]); acc[7]=fmaf(ov,wB.w,acc[7]);
            }
        }
        float* op = out + (b*2048 + q0 + mq)*128 + e0;
        float4 oA; oA.x=acc[0]; oA.y=acc[1]; oA.z=acc[2]; oA.w=acc[3];
        float4 oB; oB.x=acc[4]; oB.y=acc[5]; oB.z=acc[6]; oB.w=acc[7];
        *(float4*)op = oA;
        *(float4*)(op+4) = oB;
    }
}

extern "C" void kernel_launch(void* const* d_in, const int* in_sizes, int n_in,
                              void* d_out, int out_size, void* d_ws, size_t ws_size,
                              hipStream_t stream) {
    const float* h    = (const float*)d_in[0];
    const float* src  = (const float*)d_in[1];
    const float* Wq   = (const float*)d_in[2];
    const float* Wk   = (const float*)d_in[3];
    const float* Wv   = (const float*)d_in[4];
    const float* Wout = (const float*)d_in[5];
    const float* w1   = (const float*)d_in[6];
    const float* b1   = (const float*)d_in[7];
    const float* w2   = (const float*)d_in[8];
    const float* b2   = (const float*)d_in[9];
    float* out = (float*)d_out;

    unsigned short* Qb = (unsigned short*)d_ws;       // 524288 bf16
    unsigned short* Kb = Qb + 524288;                 // 524288 bf16
    unsigned short* Vt = Kb + 524288;                 // 524288 bf16 (transposed)

    qkv_kernel<<<dim3(128,12), 256, 0, stream>>>(h, Wq, Wk, Wv, Qb, Kb, Vt);
    attn_kernel<<<dim3(128,2), 256, 0, stream>>>(src, Qb, Kb, Vt, w1, b1, w2, b2, Wout, out);
}

// Round 2
// 322.138 us; speedup vs baseline: 1.0578x; 1.0578x over previous
//
#include <hip/hip_runtime.h>

typedef __attribute__((ext_vector_type(8))) short bf16x8;
typedef __attribute__((ext_vector_type(4))) float f32x4;

#define OUT0 524288           // B*G*E
#define SRC_CH_STRIDE 8388608 // B*G*G = 2*2048*2048
#define PART_HEAD 544         // m[16] + l[16] + O[16*32]
#define PART_SLICE 2176       // 4 heads * 544

__device__ __forceinline__ unsigned short f2bf(float x){
    unsigned u = __builtin_bit_cast(unsigned, x);
    u += 0x7FFFu + ((u >> 16) & 1u);
    return (unsigned short)(u >> 16);
}

// ---------------- kernel 1: QKV projection ----------------
// grid (128 row-tiles of 32, 12 = 3 mats x 4 heads), block 256
// Q,K -> bf16 [b][g][head*32+k] ; V -> bf16 transposed [b][head*32+v][g]
__global__ __launch_bounds__(256) void qkv_kernel(
    const float* __restrict__ hsrc,
    const float* __restrict__ Wq, const float* __restrict__ Wk, const float* __restrict__ Wv,
    unsigned short* __restrict__ Qb, unsigned short* __restrict__ Kb, unsigned short* __restrict__ Vt)
{
    __shared__ float hs[32*128];
    __shared__ float ws[128*32];
    const int t = threadIdx.x;
    const int g0 = blockIdx.x * 32;
    const int mat = blockIdx.y;
    const int mt = mat >> 2, head = mat & 3;
    {
        const float4* s = (const float4*)(hsrc + g0*128);
        float4* d = (float4*)hs;
        #pragma unroll
        for (int i=0;i<4;i++) d[t + i*256] = s[t + i*256];
        const float* W = (mt==0?Wq:(mt==1?Wk:Wv)) + head*4096;
        const float4* s2 = (const float4*)W;
        float4* d2 = (float4*)ws;
        #pragma unroll
        for (int i=0;i<4;i++) d2[t + i*256] = s2[t + i*256];
    }
    __syncthreads();
    const int r = t >> 3;          // 0..31 row in tile
    const int k0 = (t & 7) * 4;    // 0..28 out col group
    float a0=0.f,a1=0.f,a2=0.f,a3=0.f;
    const float* hr = hs + r*128;
    #pragma unroll 8
    for (int d=0; d<128; d++){
        float hv = hr[d];
        float4 w4 = *(const float4*)(ws + d*32 + k0);
        a0 = fmaf(hv, w4.x, a0); a1 = fmaf(hv, w4.y, a1);
        a2 = fmaf(hv, w4.z, a2); a3 = fmaf(hv, w4.w, a3);
    }
    const int row_g = g0 + r;
    if (mt == 2){
        const int b = row_g >> 11, g = row_g & 2047;
        unsigned short* dst = Vt + ((b*128 + head*32 + k0) * 2048) + g;
        dst[0] = f2bf(a0); dst[2048] = f2bf(a1); dst[4096] = f2bf(a2); dst[6144] = f2bf(a3);
    } else {
        unsigned short* dst = (mt==0?Qb:Kb) + row_g*128 + head*32 + k0;
        dst[0]=f2bf(a0); dst[1]=f2bf(a1); dst[2]=f2bf(a2); dst[3]=f2bf(a3);
    }
}

// ---------------- kernel 2: fused attention, p-sliced ----------------
// grid (128 q-tiles of 16, B=2, 4 p-slices), block 256 = 4 waves (wave == head)
// Writes per-head UN-normalized partials (m,l,O) to ws.
__global__ __launch_bounds__(256) void attn_kernel(
    const float* __restrict__ src,
    const unsigned short* __restrict__ Qb,
    const unsigned short* __restrict__ Kb,
    const unsigned short* __restrict__ Vt,
    const float* __restrict__ w1g, const float* __restrict__ b1g,
    const float* __restrict__ w2g, const float* __restrict__ b2g,
    float* __restrict__ part,
    float* __restrict__ out)
{
    __shared__ __align__(16) float S_lds[4*16*68];            // scores/logits, +4 pad
    __shared__ __align__(16) unsigned short Pb_lds[4*16*72];  // P bf16, +8 pad
    __shared__ __align__(16) float wt[112];                   // MLP weights
    __shared__ __align__(16) float m_lds[64];
    __shared__ __align__(16) float l_lds[64];
    __shared__ __align__(16) float alpha_lds[64];

    const int t = threadIdx.x;
    const int lane = t & 63;
    const int c = t >> 6;            // head = wave
    const int quad = lane >> 4;
    const int lrow = lane & 15;
    const int q0 = blockIdx.x * 16;
    const int b = blockIdx.y;
    const int s = blockIdx.z;
    const int pbase = s * 512;

    if (t < 64) wt[t] = w1g[t];
    else if (t < 72) wt[t] = b1g[t-64];
    else if (t < 104) wt[t] = w2g[t-72];
    else if (t < 108) wt[t] = b2g[t-104];
    if (t < 64){ m_lds[t] = -1e30f; l_lds[t] = 0.f; alpha_lds[t] = 0.f; }

    // Q fragment: A[m=lane&15][k=quad*8+j], kd=32 exactly one K-step
    const bf16x8 qf = *(const bf16x8*)(Qb + (b*2048 + q0 + lrow)*128 + c*32 + quad*8);

    const int mq = t >> 4;           // MLP cell row 0..15
    const int mp = (t & 15) * 4;     // MLP cell col group
    const int srcbase0 = (b*2048 + q0 + mq)*2048 + mp;

    f32x4 o0 = {0.f,0.f,0.f,0.f};    // v 0..15
    f32x4 o1 = {0.f,0.f,0.f,0.f};    // v 16..31
    const f32x4 zero4 = {0.f,0.f,0.f,0.f};

    __syncthreads();

    for (int p0 = pbase; p0 < pbase + 512; p0 += 64){
        // ---- phase 1: src loads (+write-through) and score MFMAs ----
        float4 r4[4];
        #pragma unroll
        for (int ch=0; ch<4; ch++)
            r4[ch] = *(const float4*)(src + srcbase0 + ch*SRC_CH_STRIDE + p0);
        #pragma unroll
        for (int sub=0; sub<4; sub++){
            const bf16x8 kf = *(const bf16x8*)(Kb + (b*2048 + p0 + sub*16 + lrow)*128 + c*32 + quad*8);
            f32x4 sacc = __builtin_amdgcn_mfma_f32_16x16x32_bf16(qf, kf, zero4, 0, 0, 0);
            float* Sp = S_lds + (c*16 + quad*4)*68 + sub*16 + lrow;
            Sp[0] = sacc[0]; Sp[68] = sacc[1]; Sp[136] = sacc[2]; Sp[204] = sacc[3];
        }
        #pragma unroll
        for (int ch=0; ch<4; ch++)
            *(float4*)(out + OUT0 + srcbase0 + ch*SRC_CH_STRIDE + p0) = r4[ch];
        __syncthreads();

        // ---- phase 3: per-cell MLP (8 -> relu8 -> 4), logits back into S in place ----
        {
            float xs[4][4], xr[4][4];
            #pragma unroll
            for (int ch=0; ch<4; ch++){
                float4 v = *(const float4*)(S_lds + (ch*16 + mq)*68 + mp);
                xs[ch][0]=v.x; xs[ch][1]=v.y; xs[ch][2]=v.z; xs[ch][3]=v.w;
                xr[ch][0]=r4[ch].x; xr[ch][1]=r4[ch].y; xr[ch][2]=r4[ch].z; xr[ch][3]=r4[ch].w;
            }
            float z[4][4];
            #pragma unroll
            for (int cc=0; cc<4; cc++){
                float bb = wt[104+cc];
                #pragma unroll
                for (int cell=0; cell<4; cell++) z[cc][cell] = bb;
            }
            #pragma unroll
            for (int j=0; j<8; j++){
                float w0 = wt[j*8+0], w1v = wt[j*8+1], w2v = wt[j*8+2], w3 = wt[j*8+3];
                float w4v = wt[j*8+4], w5 = wt[j*8+5], w6 = wt[j*8+6], w7 = wt[j*8+7];
                float bj = wt[64+j];
                float hcell[4];
                #pragma unroll
                for (int cell=0; cell<4; cell++){
                    float v = bj;
                    v = fmaf(w0, xs[0][cell], v);
                    v = fmaf(w1v, xs[1][cell], v);
                    v = fmaf(w2v, xs[2][cell], v);
                    v = fmaf(w3, xs[3][cell], v);
                    v = fmaf(w4v, xr[0][cell], v);
                    v = fmaf(w5, xr[1][cell], v);
                    v = fmaf(w6, xr[2][cell], v);
                    v = fmaf(w7, xr[3][cell], v);
                    hcell[cell] = fmaxf(v, 0.f);
                }
                #pragma unroll
                for (int cc=0; cc<4; cc++){
                    float wv = wt[72 + cc*8 + j];
                    #pragma unroll
                    for (int cell=0; cell<4; cell++) z[cc][cell] = fmaf(wv, hcell[cell], z[cc][cell]);
                }
            }
            #pragma unroll
            for (int ch=0; ch<4; ch++){
                float4 v; v.x=z[ch][0]; v.y=z[ch][1]; v.z=z[ch][2]; v.w=z[ch][3];
                *(float4*)(S_lds + (ch*16 + mq)*68 + mp) = v;
            }
        }
        __syncthreads();

        // ---- phase 5: online softmax over this 64-wide p-tile ----
        {
            const int rowid = t >> 2;        // flat (head*16+q), 4 lanes per row
            const int seg = t & 3;
            const float* Sp = S_lds + rowid*68 + seg*16;
            float4 xa = *(const float4*)(Sp);
            float4 xb = *(const float4*)(Sp+4);
            float4 xc = *(const float4*)(Sp+8);
            float4 xd = *(const float4*)(Sp+12);
            float x[16];
            x[0]=xa.x; x[1]=xa.y; x[2]=xa.z; x[3]=xa.w;
            x[4]=xb.x; x[5]=xb.y; x[6]=xb.z; x[7]=xb.w;
            x[8]=xc.x; x[9]=xc.y; x[10]=xc.z; x[11]=xc.w;
            x[12]=xd.x; x[13]=xd.y; x[14]=xd.z; x[15]=xd.w;
            float mloc = x[0];
            #pragma unroll
            for (int i=1;i<16;i++) mloc = fmaxf(mloc, x[i]);
            mloc = fmaxf(mloc, __shfl_xor(mloc, 1));
            mloc = fmaxf(mloc, __shfl_xor(mloc, 2));
            float m_old = m_lds[rowid];
            float m_new = fmaxf(m_old, mloc);
            float ssum = 0.f;
            unsigned pk[8];
            #pragma unroll
            for (int i=0;i<8;i++){
                float e0 = __expf(x[2*i] - m_new);
                float e1 = __expf(x[2*i+1] - m_new);
                ssum += e0 + e1;
                pk[i] = (unsigned)f2bf(e0) | ((unsigned)f2bf(e1) << 16);
            }
            ssum += __shfl_xor(ssum, 1);
            ssum += __shfl_xor(ssum, 2);
            uint4* Pp = (uint4*)(Pb_lds + rowid*72 + seg*16);
            Pp[0] = make_uint4(pk[0],pk[1],pk[2],pk[3]);
            Pp[1] = make_uint4(pk[4],pk[5],pk[6],pk[7]);
            if (seg == 0){
                float alpha = __expf(m_old - m_new);
                m_lds[rowid] = m_new;
                alpha_lds[rowid] = alpha;
                l_lds[rowid] = fmaf(l_lds[rowid], alpha, ssum);
            }
        }
        __syncthreads();

        // ---- phase 7: rescale O, P@V via MFMA (V read direct from global, transposed) ----
        {
            float4 a4 = *(const float4*)(alpha_lds + c*16 + quad*4);
            o0[0]*=a4.x; o0[1]*=a4.y; o0[2]*=a4.z; o0[3]*=a4.w;
            o1[0]*=a4.x; o1[1]*=a4.y; o1[2]*=a4.z; o1[3]*=a4.w;
            #pragma unroll
            for (int chunk=0; chunk<2; chunk++){
                const bf16x8 pf = *(const bf16x8*)(Pb_lds + (c*16 + lrow)*72 + chunk*32 + quad*8);
                const bf16x8 v0 = *(const bf16x8*)(Vt + (b*128 + c*32 + lrow)*2048 + p0 + chunk*32 + quad*8);
                const bf16x8 v1 = *(const bf16x8*)(Vt + (b*128 + c*32 + 16 + lrow)*2048 + p0 + chunk*32 + quad*8);
                o0 = __builtin_amdgcn_mfma_f32_16x16x32_bf16(pf, v0, o0, 0, 0, 0);
                o1 = __builtin_amdgcn_mfma_f32_16x16x32_bf16(pf, v1, o1, 0, 0, 0);
            }
        }
    }

    // ---- write per-head partials: m[16], l[16], O[16][32] (un-normalized) ----
    {
        float* P = part + (((b*128 + blockIdx.x)*4 + s)*4 + c) * PART_HEAD;
        if (lane < 16){
            P[lane]      = m_lds[c*16 + lane];
            P[16 + lane] = l_lds[c*16 + lane];
        }
        #pragma unroll
        for (int r=0;r<4;r++){
            P[32 + (quad*4 + r)*32 + lrow]      = o0[r];
            P[32 + (quad*4 + r)*32 + 16 + lrow] = o1[r];
        }
    }
}

// ---------------- kernel 3: slice combine + output projection ----------------
// grid (128, 2), block 256
__global__ __launch_bounds__(256) void combine_kernel(
    const float* __restrict__ part,
    const float* __restrict__ Wout,
    float* __restrict__ out)
{
    __shared__ __align__(16) float O_lds[64*33];
    const int t = threadIdx.x;
    const int qt = blockIdx.x, b = blockIdx.y;

    if (t < 64){
        const int c = t >> 4, q = t & 15;
        const float* P0 = part + (((b*128 + qt)*4 + 0)*4 + c) * PART_HEAD;
        float m0 = P0[q], m1 = P0[PART_SLICE + q], m2 = P0[2*PART_SLICE + q], m3 = P0[3*PART_SLICE + q];
        float M = fmaxf(fmaxf(m0, m1), fmaxf(m2, m3));
        float w0 = __expf(m0 - M), w1 = __expf(m1 - M), w2 = __expf(m2 - M), w3 = __expf(m3 - M);
        float L = P0[16+q]*w0 + P0[PART_SLICE+16+q]*w1 + P0[2*PART_SLICE+16+q]*w2 + P0[3*PART_SLICE+16+q]*w3;
        float invL = 1.f / L;
        const float* O0 = P0 + 32 + q*32;
        float* dst = O_lds + t*33;
        #pragma unroll
        for (int v4 = 0; v4 < 8; v4++){
            float4 a  = *(const float4*)(O0 + v4*4);
            float4 bb = *(const float4*)(O0 + PART_SLICE + v4*4);
            float4 cc = *(const float4*)(O0 + 2*PART_SLICE + v4*4);
            float4 dd = *(const float4*)(O0 + 3*PART_SLICE + v4*4);
            dst[v4*4+0] = (a.x*w0 + bb.x*w1 + cc.x*w2 + dd.x*w3) * invL;
            dst[v4*4+1] = (a.y*w0 + bb.y*w1 + cc.y*w2 + dd.y*w3) * invL;
            dst[v4*4+2] = (a.z*w0 + bb.z*w1 + cc.z*w2 + dd.z*w3) * invL;
            dst[v4*4+3] = (a.w*w0 + bb.w*w1 + cc.w*w2 + dd.w*w3) * invL;
        }
    }
    __syncthreads();

    // projection: out[b, q0+mq, :] = sum_c O[c, mq, :] @ Wout[c]
    {
        const int mq = t >> 4;
        const int e0 = (t & 15) * 8;
        float acc[8];
        #pragma unroll
        for (int i=0;i<8;i++) acc[i]=0.f;
        #pragma unroll
        for (int cc=0; cc<4; cc++){
            const float* OhRow = O_lds + (cc*16 + mq)*33;
            const float* Wrow = Wout + cc*32*128 + e0;
            #pragma unroll 4
            for (int v=0; v<32; v++){
                float ov = OhRow[v];
                float4 wA = *(const float4*)(Wrow + v*128);
                float4 wB = *(const float4*)(Wrow + v*128 + 4);
                acc[0]=fmaf(ov,wA.x,acc[0]); acc[1]=fmaf(ov,wA.y,acc[1]);
                acc[2]=fmaf(ov,wA.z,acc[2]); acc[3]=fmaf(ov,wA.w,acc[3]);
                acc[4]=fmaf(ov,wB.x,acc[4]); acc[5]=fmaf(ov,wB.y,acc[5]);
                acc[6]=fmaf(ov,wB.z,acc[6]); acc[7]=fmaf(ov,wB.w,acc[7]);
            }
        }
        float* op = out + (b*2048 + qt*16 + mq)*128 + e0;
        float4 oA; oA.x=acc[0]; oA.y=acc[1]; oA.z=acc[2]; oA.w=acc[3];
        float4 oB; oB.x=acc[4]; oB.y=acc[5]; oB.z=acc[6]; oB.w=acc[7];
        *(float4*)op = oA;
        *(float4*)(op+4) = oB;
    }
}

extern "C" void kernel_launch(void* const* d_in, const int* in_sizes, int n_in,
                              void* d_out, int out_size, void* d_ws, size_t ws_size,
                              hipStream_t stream) {
    const float* h    = (const float*)d_in[0];
    const float* src  = (const float*)d_in[1];
    const float* Wq   = (const float*)d_in[2];
    const float* Wk   = (const float*)d_in[3];
    const float* Wv   = (const float*)d_in[4];
    const float* Wout = (const float*)d_in[5];
    const float* w1   = (const float*)d_in[6];
    const float* b1   = (const float*)d_in[7];
    const float* w2   = (const float*)d_in[8];
    const float* b2   = (const float*)d_in[9];
    float* out = (float*)d_out;

    unsigned short* Qb = (unsigned short*)d_ws;       // 524288 bf16 = 1 MB
    unsigned short* Kb = Qb + 524288;                 // 1 MB
    unsigned short* Vt = Kb + 524288;                 // 1 MB (transposed)
    float* part = (float*)((char*)d_ws + 3*1048576);  // 1024 blocks * 4 heads * 544 floats = 8.9 MB

    qkv_kernel<<<dim3(128,12), 256, 0, stream>>>(h, Wq, Wk, Wv, Qb, Kb, Vt);
    attn_kernel<<<dim3(128,2,4), 256, 0, stream>>>(src, Qb, Kb, Vt, w1, b1, w2, b2, part, out);
    combine_kernel<<<dim3(128,2), 256, 0, stream>>>(part, Wout, out);
}